// Round 1
// baseline (995.814 us; speedup 1.0000x reference)
//
#include <hip/hip_runtime.h>
#include <math.h>

// Problem constants
#define BB   32     // batch
#define NN   2048   // input capsules
#define KK   16     // input dim
#define CC   32     // output capsules
#define DD   32     // capsule dim
#define NCOL 1024   // CC*DD
#define N_PER_BLOCK 8   // 2048 n / 256 blocks

// One routing iteration, fused:
//   per n: U[b, c*32+d] = sum_k u[b,n,k] * W[n,k,c*32+d]
//          logit[b,c]   = sum_d U[b,c,d] * onorm[b,c,d]   (onorm==0 -> uniform softmax, stage 0)
//          c[b,:]       = softmax over capsules
//          opart[b,:]  += c[b,cap] * U[b,:]
// Block owns ALL 32 b for its 8 n's => W read exactly once per stage.
// Thread decomposition (1024 threads): bg = tid>>7 (4 b's each), cq = tid&127
// -> cols {cq*4..+3} and {+512..}, i.e. capsule i0=cq>>3 and i0+16, j-quad jq=cq&7.
__global__ __launch_bounds__(1024) void caps_stage(
    const float* __restrict__ u, const float* __restrict__ W,
    const float* __restrict__ onorm, float* __restrict__ oacc)
{
    __shared__ float u_sh[BB * KK];        // u[:, n, :]
    __shared__ float logit_sh[BB * CC];
    __shared__ float c_sh[BB * CC];

    const int tid = threadIdx.x;
    const int bg  = tid >> 7;        // 0..7
    const int cq  = tid & 127;       // 0..127
    const int i0  = cq >> 3;         // capsule 0..15 (second set +16)
    const int jq  = cq & 7;          // j quad
    const int b0  = bg << 2;         // first of 4 b's
    const int c0  = cq << 2;         // first col (second set +512)

    float opart[2][4][4];
#pragma unroll
    for (int s = 0; s < 2; ++s)
#pragma unroll
        for (int bb = 0; bb < 4; ++bb)
#pragma unroll
            for (int m = 0; m < 4; ++m) opart[s][bb][m] = 0.f;

    for (int nn = 0; nn < N_PER_BLOCK; ++nn) {
        const int n = blockIdx.x * N_PER_BLOCK + nn;

        // stage u[:, n, :] (32x16 floats) into LDS
        if (tid < BB * KK) {
            u_sh[tid] = u[(size_t)(tid >> 4) * (NN * KK) + (size_t)n * KK + (tid & 15)];
        }
        __syncthreads();   // (A) u_sh ready; also fences prev-iter c_sh reads

        // ---- U = u . W for my 4 b x 8 cols ----
        float accU[2][4][4];
#pragma unroll
        for (int s = 0; s < 2; ++s)
#pragma unroll
            for (int bb = 0; bb < 4; ++bb)
#pragma unroll
                for (int m = 0; m < 4; ++m) accU[s][bb][m] = 0.f;

        const float* Wn = W + (size_t)n * (KK * NCOL);
#pragma unroll
        for (int k4 = 0; k4 < KK; k4 += 4) {
            float4 uu[4];
#pragma unroll
            for (int bb = 0; bb < 4; ++bb)
                uu[bb] = *(const float4*)&u_sh[(b0 + bb) * KK + k4];
#pragma unroll
            for (int kk = 0; kk < 4; ++kk) {
                const float4 w0 = *(const float4*)(Wn + (size_t)(k4 + kk) * NCOL + c0);
                const float4 w1 = *(const float4*)(Wn + (size_t)(k4 + kk) * NCOL + c0 + 512);
#pragma unroll
                for (int bb = 0; bb < 4; ++bb) {
                    const float uv = (kk == 0) ? uu[bb].x : (kk == 1) ? uu[bb].y
                                   : (kk == 2) ? uu[bb].z : uu[bb].w;
                    accU[0][bb][0] = fmaf(uv, w0.x, accU[0][bb][0]);
                    accU[0][bb][1] = fmaf(uv, w0.y, accU[0][bb][1]);
                    accU[0][bb][2] = fmaf(uv, w0.z, accU[0][bb][2]);
                    accU[0][bb][3] = fmaf(uv, w0.w, accU[0][bb][3]);
                    accU[1][bb][0] = fmaf(uv, w1.x, accU[1][bb][0]);
                    accU[1][bb][1] = fmaf(uv, w1.y, accU[1][bb][1]);
                    accU[1][bb][2] = fmaf(uv, w1.z, accU[1][bb][2]);
                    accU[1][bb][3] = fmaf(uv, w1.w, accU[1][bb][3]);
                }
            }
        }

        // ---- logits: dot with onorm, reduce over j (8 lanes, bits 0..2) ----
        float lp[2][4];
#pragma unroll
        for (int s = 0; s < 2; ++s)
#pragma unroll
            for (int bb = 0; bb < 4; ++bb) {
                const float4 on4 = *(const float4*)(
                    onorm + ((size_t)(b0 + bb) * CC + (i0 + s * 16)) * DD + (jq << 2));
                float p = accU[s][bb][0] * on4.x + accU[s][bb][1] * on4.y
                        + accU[s][bb][2] * on4.z + accU[s][bb][3] * on4.w;
                p += __shfl_xor(p, 1);
                p += __shfl_xor(p, 2);
                p += __shfl_xor(p, 4);
                lp[s][bb] = p;
            }
        if (jq == 0) {
#pragma unroll
            for (int s = 0; s < 2; ++s)
#pragma unroll
                for (int bb = 0; bb < 4; ++bb)
                    logit_sh[(b0 + bb) * CC + i0 + s * 16] = lp[s][bb];
        }
        __syncthreads();   // (B) logits ready

        // ---- softmax over capsules: thread = (b = tid>>5, i = tid&31) ----
        {
            const int b  = tid >> 5;
            const int ii = tid & 31;
            float l = logit_sh[b * CC + ii];
            float mx = l;
#pragma unroll
            for (int msk = 16; msk >= 1; msk >>= 1)
                mx = fmaxf(mx, __shfl_xor(mx, msk));
            const float e = __expf(l - mx);
            float sm = e;
#pragma unroll
            for (int msk = 16; msk >= 1; msk >>= 1)
                sm += __shfl_xor(sm, msk);
            c_sh[b * CC + ii] = e / sm;
        }
        __syncthreads();   // (C) c ready

        // ---- opart += c * U ----
#pragma unroll
        for (int s = 0; s < 2; ++s)
#pragma unroll
            for (int bb = 0; bb < 4; ++bb) {
                const float cc = c_sh[(b0 + bb) * CC + i0 + s * 16];
#pragma unroll
                for (int m = 0; m < 4; ++m)
                    opart[s][bb][m] = fmaf(cc, accU[s][bb][m], opart[s][bb][m]);
            }
        // next-iter (A) barrier fences c_sh reads vs. (B)-phase rewrite
    }

    // flush partials (device-scope atomics, cross-XCD safe)
#pragma unroll
    for (int s = 0; s < 2; ++s)
#pragma unroll
        for (int bb = 0; bb < 4; ++bb)
#pragma unroll
            for (int m = 0; m < 4; ++m)
                atomicAdd(&oacc[(size_t)(b0 + bb) * NCOL + c0 + (s << 9) + m],
                          opart[s][bb][m]);
}

// l2_normalize rows of 32: onorm = o * rsqrt(max(sum(o^2), 1e-12))
__global__ void caps_norm(const float* __restrict__ oacc, float* __restrict__ onorm)
{
    const int t = blockIdx.x * blockDim.x + threadIdx.x;   // 0..1023 = (b,i)
    const float4* src = (const float4*)(oacc + (size_t)t * DD);
    float4 v[8];
    float s2 = 0.f;
#pragma unroll
    for (int q = 0; q < 8; ++q) {
        v[q] = src[q];
        s2 += v[q].x * v[q].x + v[q].y * v[q].y + v[q].z * v[q].z + v[q].w * v[q].w;
    }
    const float r = rsqrtf(fmaxf(s2, 1e-12f));
    float4* dst = (float4*)(onorm + (size_t)t * DD);
#pragma unroll
    for (int q = 0; q < 8; ++q) {
        float4 o;
        o.x = v[q].x * r; o.y = v[q].y * r; o.z = v[q].z * r; o.w = v[q].w * r;
        dst[q] = o;
    }
}

// squash in-place: x * (s2/(1+s2)) / sqrt(s2 + 1e-7)
__global__ void caps_squash(float* __restrict__ io)
{
    const int t = blockIdx.x * blockDim.x + threadIdx.x;   // 0..1023
    float4* p = (float4*)(io + (size_t)t * DD);
    float4 v[8];
    float s2 = 0.f;
#pragma unroll
    for (int q = 0; q < 8; ++q) {
        v[q] = p[q];
        s2 += v[q].x * v[q].x + v[q].y * v[q].y + v[q].z * v[q].z + v[q].w * v[q].w;
    }
    const float scale = (s2 / (1.f + s2)) / sqrtf(s2 + 1e-7f);
#pragma unroll
    for (int q = 0; q < 8; ++q) {
        float4 o;
        o.x = v[q].x * scale; o.y = v[q].y * scale;
        o.z = v[q].z * scale; o.w = v[q].w * scale;
        p[q] = o;
    }
}

extern "C" void kernel_launch(void* const* d_in, const int* in_sizes, int n_in,
                              void* d_out, int out_size, void* d_ws, size_t ws_size,
                              hipStream_t stream)
{
    const float* u = (const float*)d_in[0];   // (32, 2048, 16)
    const float* W = (const float*)d_in[1];   // (2048, 16, 1024)
    float* out   = (float*)d_out;             // (32, 32, 32) — doubles as o-accumulator
    float* onorm = (float*)d_ws;              // 128 KB scratch: normalized o

    const size_t obytes = (size_t)BB * NCOL * sizeof(float);   // 128 KB

    // onorm = 0 => logits 0 => softmax uniform 1/32 (exactly iteration 0)
    hipMemsetAsync(onorm, 0, obytes, stream);

    for (int it = 0; it < 3; ++it) {
        hipMemsetAsync(out, 0, obytes, stream);
        caps_stage<<<NN / N_PER_BLOCK, 1024, 0, stream>>>(u, W, onorm, out);
        if (it < 2) caps_norm<<<4, 256, 0, stream>>>(out, onorm);
    }
    caps_squash<<<4, 256, 0, stream>>>(out);
}

// Round 2
// 565.411 us; speedup vs baseline: 1.7612x; 1.7612x over previous
//
#include <hip/hip_runtime.h>
#include <math.h>

// Problem constants
#define BB   32     // batch
#define NN   2048   // input capsules
#define KK   16     // input dim
#define CC   32     // output capsules
#define DD   32     // capsule dim
#define NCOL 1024   // CC*DD
#define N_PER_BLOCK 8   // 2048 n / 256 blocks
#define OSZ  (BB * NCOL)          // 32768 floats = one full o/partial image
#define NSLICE 8                  // reduce tree fan-in stage 1: 256 -> 8

// One routing iteration, fused:
//   per n: U[b, c*32+d] = sum_k u[b,n,k] * W[n,k,c*32+d]
//          logit[b,c]   = sum_d U[b,c,d] * onorm[b,c,d]   (onorm==0 -> uniform softmax, stage 0)
//          c[b,:]       = softmax over capsules
//          opart[b,:]  += c[b,cap] * U[b,:]
// Block owns ALL 32 b for its 8 n's => W read exactly once per stage.
// Thread decomposition (1024 threads): bg = tid>>7 (4 b's each), cq = tid&127
// -> cols {cq*4..+3} and {+512..}, i.e. capsule i0=cq>>3 and i0+16, j-quad jq=cq&7.
// Partials go to ws (no atomics: 256-way atomic contention cost 300 MB HBM RMW
// traffic and 3x kernel time in round 1).
__global__ __launch_bounds__(1024) void caps_stage(
    const float* __restrict__ u, const float* __restrict__ W,
    const float* __restrict__ onorm, float* __restrict__ part)
{
    __shared__ float u_sh[BB * KK];        // u[:, n, :]
    __shared__ float logit_sh[BB * CC];
    __shared__ float c_sh[BB * CC];

    const int tid = threadIdx.x;
    const int bg  = tid >> 7;        // 0..7
    const int cq  = tid & 127;       // 0..127
    const int i0  = cq >> 3;         // capsule 0..15 (second set +16)
    const int jq  = cq & 7;          // j quad
    const int b0  = bg << 2;         // first of 4 b's
    const int c0  = cq << 2;         // first col (second set +512)

    float opart[2][4][4];
#pragma unroll
    for (int s = 0; s < 2; ++s)
#pragma unroll
        for (int bb = 0; bb < 4; ++bb)
#pragma unroll
            for (int m = 0; m < 4; ++m) opart[s][bb][m] = 0.f;

    for (int nn = 0; nn < N_PER_BLOCK; ++nn) {
        const int n = blockIdx.x * N_PER_BLOCK + nn;

        // stage u[:, n, :] (32x16 floats) into LDS
        if (tid < BB * KK) {
            u_sh[tid] = u[(size_t)(tid >> 4) * (NN * KK) + (size_t)n * KK + (tid & 15)];
        }
        __syncthreads();   // (A) u_sh ready; also fences prev-iter c_sh reads

        // ---- U = u . W for my 4 b x 8 cols ----
        float accU[2][4][4];
#pragma unroll
        for (int s = 0; s < 2; ++s)
#pragma unroll
            for (int bb = 0; bb < 4; ++bb)
#pragma unroll
                for (int m = 0; m < 4; ++m) accU[s][bb][m] = 0.f;

        const float* Wn = W + (size_t)n * (KK * NCOL);
#pragma unroll
        for (int k4 = 0; k4 < KK; k4 += 4) {
            float4 uu[4];
#pragma unroll
            for (int bb = 0; bb < 4; ++bb)
                uu[bb] = *(const float4*)&u_sh[(b0 + bb) * KK + k4];
#pragma unroll
            for (int kk = 0; kk < 4; ++kk) {
                const float4 w0 = *(const float4*)(Wn + (size_t)(k4 + kk) * NCOL + c0);
                const float4 w1 = *(const float4*)(Wn + (size_t)(k4 + kk) * NCOL + c0 + 512);
#pragma unroll
                for (int bb = 0; bb < 4; ++bb) {
                    const float uv = (kk == 0) ? uu[bb].x : (kk == 1) ? uu[bb].y
                                   : (kk == 2) ? uu[bb].z : uu[bb].w;
                    accU[0][bb][0] = fmaf(uv, w0.x, accU[0][bb][0]);
                    accU[0][bb][1] = fmaf(uv, w0.y, accU[0][bb][1]);
                    accU[0][bb][2] = fmaf(uv, w0.z, accU[0][bb][2]);
                    accU[0][bb][3] = fmaf(uv, w0.w, accU[0][bb][3]);
                    accU[1][bb][0] = fmaf(uv, w1.x, accU[1][bb][0]);
                    accU[1][bb][1] = fmaf(uv, w1.y, accU[1][bb][1]);
                    accU[1][bb][2] = fmaf(uv, w1.z, accU[1][bb][2]);
                    accU[1][bb][3] = fmaf(uv, w1.w, accU[1][bb][3]);
                }
            }
        }

        // ---- logits: dot with onorm, reduce over j (8 lanes, bits 0..2) ----
        float lp[2][4];
#pragma unroll
        for (int s = 0; s < 2; ++s)
#pragma unroll
            for (int bb = 0; bb < 4; ++bb) {
                const float4 on4 = *(const float4*)(
                    onorm + ((size_t)(b0 + bb) * CC + (i0 + s * 16)) * DD + (jq << 2));
                float p = accU[s][bb][0] * on4.x + accU[s][bb][1] * on4.y
                        + accU[s][bb][2] * on4.z + accU[s][bb][3] * on4.w;
                p += __shfl_xor(p, 1);
                p += __shfl_xor(p, 2);
                p += __shfl_xor(p, 4);
                lp[s][bb] = p;
            }
        if (jq == 0) {
#pragma unroll
            for (int s = 0; s < 2; ++s)
#pragma unroll
                for (int bb = 0; bb < 4; ++bb)
                    logit_sh[(b0 + bb) * CC + i0 + s * 16] = lp[s][bb];
        }
        __syncthreads();   // (B) logits ready

        // ---- softmax over capsules: thread = (b = tid>>5, i = tid&31) ----
        {
            const int b  = tid >> 5;
            const int ii = tid & 31;
            float l = logit_sh[b * CC + ii];
            float mx = l;
#pragma unroll
            for (int msk = 16; msk >= 1; msk >>= 1)
                mx = fmaxf(mx, __shfl_xor(mx, msk));
            const float e = __expf(l - mx);
            float sm = e;
#pragma unroll
            for (int msk = 16; msk >= 1; msk >>= 1)
                sm += __shfl_xor(sm, msk);
            c_sh[b * CC + ii] = e / sm;
        }
        __syncthreads();   // (C) c ready

        // ---- opart += c * U ----
#pragma unroll
        for (int s = 0; s < 2; ++s)
#pragma unroll
            for (int bb = 0; bb < 4; ++bb) {
                const float cc = c_sh[(b0 + bb) * CC + i0 + s * 16];
#pragma unroll
                for (int m = 0; m < 4; ++m)
                    opart[s][bb][m] = fmaf(cc, accU[s][bb][m], opart[s][bb][m]);
            }
        // next-iter (A) barrier fences c_sh reads vs. (B)-phase rewrite
    }

    // flush partials, coalesced float4 stores (1 KB contiguous per wave per (s,bb))
    float* my = part + (size_t)blockIdx.x * OSZ;
#pragma unroll
    for (int s = 0; s < 2; ++s)
#pragma unroll
        for (int bb = 0; bb < 4; ++bb) {
            float4 v;
            v.x = opart[s][bb][0]; v.y = opart[s][bb][1];
            v.z = opart[s][bb][2]; v.w = opart[s][bb][3];
            *(float4*)&my[(b0 + bb) * NCOL + c0 + (s << 9)] = v;
        }
}

// Level-1 reduce: 256 partial images -> NSLICE slice images.
// grid 256 x 256; gid = slice(3b) | q(13b); each thread sums 32 partials of quad q.
__global__ __launch_bounds__(256) void caps_reduce1(
    const float* __restrict__ part, float* __restrict__ ws2)
{
    const int gid   = blockIdx.x * 256 + threadIdx.x;     // 0..65535
    const int slice = gid >> 13;                          // 0..7
    const int q     = gid & 8191;                         // col-quad 0..8191
    float4 acc = make_float4(0.f, 0.f, 0.f, 0.f);
    const float* p = part + ((size_t)slice * 32) * OSZ + (q << 2);
#pragma unroll 8
    for (int j = 0; j < 32; ++j) {
        const float4 v = *(const float4*)(p + (size_t)j * OSZ);
        acc.x += v.x; acc.y += v.y; acc.z += v.z; acc.w += v.w;
    }
    *(float4*)(ws2 + ((size_t)gid << 2)) = acc;
}

// Level-2 reduce + row op. mode 0: l2-normalize -> dst. mode 1: squash -> dst.
// 8192 threads; thread q handles cols [4q,4q+4); row (b,c) = q>>3 spans 8 lanes.
__global__ __launch_bounds__(256) void caps_reduce2(
    const float* __restrict__ ws2, float* __restrict__ dst, int mode)
{
    const int q = blockIdx.x * 256 + threadIdx.x;         // 0..8191
    float4 acc = make_float4(0.f, 0.f, 0.f, 0.f);
#pragma unroll
    for (int s = 0; s < NSLICE; ++s) {
        const float4 v = *(const float4*)(ws2 + ((size_t)s << 15) + (q << 2));
        acc.x += v.x; acc.y += v.y; acc.z += v.z; acc.w += v.w;
    }
    float s2 = acc.x * acc.x + acc.y * acc.y + acc.z * acc.z + acc.w * acc.w;
    s2 += __shfl_xor(s2, 1);
    s2 += __shfl_xor(s2, 2);
    s2 += __shfl_xor(s2, 4);
    float scale;
    if (mode == 0) {
        scale = rsqrtf(fmaxf(s2, 1e-12f));
    } else {
        scale = (s2 / (1.f + s2)) / sqrtf(s2 + 1e-7f);
    }
    float4 o;
    o.x = acc.x * scale; o.y = acc.y * scale;
    o.z = acc.z * scale; o.w = acc.w * scale;
    *(float4*)(dst + ((size_t)q << 2)) = o;
}

extern "C" void kernel_launch(void* const* d_in, const int* in_sizes, int n_in,
                              void* d_out, int out_size, void* d_ws, size_t ws_size,
                              hipStream_t stream)
{
    const float* u = (const float*)d_in[0];   // (32, 2048, 16)
    const float* W = (const float*)d_in[1];   // (2048, 16, 1024)
    float* out = (float*)d_out;               // (32, 32, 32)

    // ws layout: part (256 * 32768 fl = 32 MB) | ws2 (8 * 32768 fl = 1 MB) | onorm (128 KB)
    float* part  = (float*)d_ws;
    float* ws2   = part + (size_t)256 * OSZ;
    float* onorm = ws2 + (size_t)NSLICE * OSZ;

    // onorm = 0 => logits 0 => softmax uniform 1/32 (exactly iteration 0)
    hipMemsetAsync(onorm, 0, (size_t)OSZ * sizeof(float), stream);

    for (int it = 0; it < 3; ++it) {
        caps_stage<<<NN / N_PER_BLOCK, 1024, 0, stream>>>(u, W, onorm, part);
        caps_reduce1<<<256, 256, 0, stream>>>(part, ws2);
        if (it < 2)
            caps_reduce2<<<32, 256, 0, stream>>>(ws2, onorm, 0);  // l2-normalize
        else
            caps_reduce2<<<32, 256, 0, stream>>>(ws2, out, 1);    // squash -> d_out
    }
}